// Round 1
// baseline (46.930 us; speedup 1.0000x reference)
//
#include <hip/hip_runtime.h>
#include <hip/hip_bf16.h>

// Causal depthwise conv1d, B=2, C=2048, L=8192, K=4, fp32.
// y[b,c,l] = sum_{k=0}^{3} w[c,k] * x[b,c, l+k-3]   (terms with index<0 are 0)

#define B_DIM 2
#define C_DIM 2048
#define L_DIM 8192
#define K_DIM 4

__global__ __launch_bounds__(256)
void causal_dwconv1d_kernel(const float* __restrict__ x,
                            const float* __restrict__ w,
                            float* __restrict__ y) {
    const int row = blockIdx.x;            // row = b*C + c, 0..B*C-1
    const int c = row & (C_DIM - 1);

    const float4* __restrict__ xr =
        reinterpret_cast<const float4*>(x + (size_t)row * L_DIM);
    float4* __restrict__ yr =
        reinterpret_cast<float4*>(y + (size_t)row * L_DIM);

    // per-channel taps (L1-resident, broadcast across the block)
    const float w0 = w[c * K_DIM + 0];
    const float w1 = w[c * K_DIM + 1];
    const float w2 = w[c * K_DIM + 2];
    const float w3 = w[c * K_DIM + 3];

    const int nvec = L_DIM / 4;  // 2048 float4 per row

    for (int i = threadIdx.x; i < nvec; i += blockDim.x) {
        float4 v = xr[i];
        float4 p;
        if (i > 0) {
            p = xr[i - 1];   // overlapping read: served from L1/L2
        } else {
            p = make_float4(0.f, 0.f, 0.f, 0.f);  // causal zero pad
        }
        float4 o;
        o.x = w0 * p.y + w1 * p.z + w2 * p.w + w3 * v.x;
        o.y = w0 * p.z + w1 * p.w + w2 * v.x + w3 * v.y;
        o.z = w0 * p.w + w1 * v.x + w2 * v.y + w3 * v.z;
        o.w = w0 * v.x + w1 * v.y + w2 * v.z + w3 * v.w;
        yr[i] = o;
    }
}

extern "C" void kernel_launch(void* const* d_in, const int* in_sizes, int n_in,
                              void* d_out, int out_size, void* d_ws, size_t ws_size,
                              hipStream_t stream) {
    const float* x = (const float*)d_in[0];   // [B, C, L] fp32
    const float* w = (const float*)d_in[1];   // [C, 1, K] fp32
    float* y = (float*)d_out;                 // [B, C, L] fp32

    dim3 grid(B_DIM * C_DIM);   // 4096 blocks, one per (b,c) row
    dim3 block(256);
    causal_dwconv1d_kernel<<<grid, block, 0, stream>>>(x, w, y);
}

// Round 3
// 44.778 us; speedup vs baseline: 1.0481x; 1.0481x over previous
//
#include <hip/hip_runtime.h>
#include <hip/hip_bf16.h>

// Causal depthwise conv1d, B=2, C=2048, L=8192, K=4, fp32.
// y[b,c,l] = sum_{k=0}^{3} w[c,k] * x[b,c, l+k-3]   (terms with index<0 are 0)
//
// Memory-bound: 134 MB read + 134 MB write. Round-1: 46.9 us (~91% of the
// 6.3 TB/s copy ceiling). This round: non-temporal stores for y (write-once,
// never re-read) so x can stay resident in the 256 MB Infinity Cache.
// Note: __builtin_nontemporal_store needs a native clang vector type, not
// HIP's float4 class — use ext_vector_type(4).

#define B_DIM 2
#define C_DIM 2048
#define L_DIM 8192
#define K_DIM 4

typedef float f32x4 __attribute__((ext_vector_type(4)));

__global__ __launch_bounds__(256)
void causal_dwconv1d_kernel(const float* __restrict__ x,
                            const float* __restrict__ w,
                            float* __restrict__ y) {
    const int row = blockIdx.x;            // row = b*C + c, 0..B*C-1
    const int c = row & (C_DIM - 1);

    const f32x4* __restrict__ xr =
        reinterpret_cast<const f32x4*>(x + (size_t)row * L_DIM);
    f32x4* __restrict__ yr =
        reinterpret_cast<f32x4*>(y + (size_t)row * L_DIM);

    // per-channel taps (L1-resident, broadcast across the block)
    const float w0 = w[c * K_DIM + 0];
    const float w1 = w[c * K_DIM + 1];
    const float w2 = w[c * K_DIM + 2];
    const float w3 = w[c * K_DIM + 3];

    const int nvec = L_DIM / 4;  // 2048 float4 per row

    for (int i = threadIdx.x; i < nvec; i += blockDim.x) {
        f32x4 v = xr[i];
        f32x4 p;
        if (i > 0) {
            p = xr[i - 1];   // overlapping read: served from L1/L2
        } else {
            p = (f32x4){0.f, 0.f, 0.f, 0.f};  // causal zero pad
        }
        f32x4 o;
        o.x = w0 * p.y + w1 * p.z + w2 * p.w + w3 * v.x;
        o.y = w0 * p.z + w1 * p.w + w2 * v.x + w3 * v.y;
        o.z = w0 * p.w + w1 * v.x + w2 * v.y + w3 * v.z;
        o.w = w0 * v.x + w1 * v.y + w2 * v.z + w3 * v.w;
        // y is write-once, never re-read: early-evict from L2/L3 so x stays
        // Infinity-Cache-resident.
        __builtin_nontemporal_store(o, &yr[i]);
    }
}

extern "C" void kernel_launch(void* const* d_in, const int* in_sizes, int n_in,
                              void* d_out, int out_size, void* d_ws, size_t ws_size,
                              hipStream_t stream) {
    const float* x = (const float*)d_in[0];   // [B, C, L] fp32
    const float* w = (const float*)d_in[1];   // [C, 1, K] fp32
    float* y = (float*)d_out;                 // [B, C, L] fp32

    dim3 grid(B_DIM * C_DIM);   // 4096 blocks, one per (b,c) row
    dim3 block(256);
    causal_dwconv1d_kernel<<<grid, block, 0, stream>>>(x, w, y);
}